// Round 5
// baseline (411.662 us; speedup 1.0000x reference)
//
#include <hip/hip_runtime.h>

// Problem constants (Qwen3MoE attention prefill)
#define B_   2
#define S_   1024
#define HID_ 2048
#define H_   32
#define HK_  4
#define D_   128
#define NQKV ((H_ + 2 * HK_) * D_)   // 5120
#define TOK  (B_ * S_)               // 2048

typedef short bf16x8  __attribute__((ext_vector_type(8)));  // 8 bf16 (4 VGPRs)
typedef short short4v __attribute__((ext_vector_type(4)));
typedef float f32x4   __attribute__((ext_vector_type(4)));
typedef int   i32x4   __attribute__((ext_vector_type(4)));

__device__ inline short f2bf(float f) {
  unsigned u = __builtin_bit_cast(unsigned, f);
  u += 0x7fffu + ((u >> 16) & 1u);   // round-to-nearest-even
  return (short)(u >> 16);
}

// async global->LDS, 16B per lane; LDS dest is wave-uniform base + lane*16
__device__ __forceinline__ void gld_lds16(const short* g, short* l) {
  __builtin_amdgcn_global_load_lds((__attribute__((address_space(1))) void*)g,
                                   (__attribute__((address_space(3))) void*)l, 16, 0, 0);
}

// ---------------------------------------------------------------- cast fp32 -> bf16
__global__ __launch_bounds__(256) void cast_f32_bf16(const float* __restrict__ in,
                                                     short* __restrict__ out, int n4) {
  int i = blockIdx.x * 256 + threadIdx.x;
  if (i >= n4) return;
  f32x4 v = ((const f32x4*)in)[i];
  short4v o;
  o[0] = f2bf(v[0]); o[1] = f2bf(v[1]); o[2] = f2bf(v[2]); o[3] = f2bf(v[3]);
  ((short4v*)out)[i] = o;
}

// ---------------------------------------------------------------- transpose+cast: [K][N] f32 -> [N][K] bf16
__global__ __launch_bounds__(256) void transpose_cast(const float* __restrict__ in,
                                                      short* __restrict__ out,
                                                      int K, int N) {
  __shared__ float tile[32][33];
  int nb = blockIdx.x * 32, kb = blockIdx.y * 32;
  int c = threadIdx.x & 31, r0 = threadIdx.x >> 5;
#pragma unroll
  for (int i = 0; i < 4; i++) {
    int r = r0 + i * 8;
    tile[r][c] = in[(size_t)(kb + r) * N + nb + c];
  }
  __syncthreads();
#pragma unroll
  for (int i = 0; i < 4; i++) {
    int r = r0 + i * 8;
    out[(size_t)(nb + r) * K + kb + c] = f2bf(tile[c][r]);
  }
}

// ---------------------------------------------------------------- bf16 MFMA GEMM (m97 structure), split-K capable
__global__ __launch_bounds__(256) void gemm_bt128(const short* __restrict__ A,
                                                  const short* __restrict__ Bt,
                                                  float* __restrict__ C,
                                                  int M, int N, int Kfull, int klen) {
  const int tid  = threadIdx.x;
  const int m0   = blockIdx.y * 128;
  const int n0   = blockIdx.x * 128;
  const int kz0  = blockIdx.z * klen;
  const int w    = tid >> 6, lane = tid & 63;
  const int quad = lane >> 4, l16 = lane & 15;
  const int wm   = (w >> 1) * 64, wn = (w & 1) * 64;

  __shared__ short As[128 * 64];   // 16 KB, [row][64], chunks XOR-swizzled
  __shared__ short Bs[128 * 64];

  const f32x4 z = {0.f, 0.f, 0.f, 0.f};
  f32x4 acc[4][4];
#pragma unroll
  for (int i = 0; i < 4; i++)
#pragma unroll
    for (int j = 0; j < 4; j++) acc[i][j] = z;

  const int srow = lane >> 3;           // row within 8-row issue group
  const int lc   = (lane & 7) ^ srow;   // logical chunk this lane fetches

  for (int kk = 0; kk < klen; kk += 64) {
    const int k0 = kz0 + kk;
#pragma unroll
    for (int i = 0; i < 4; i++) {
      int rb = w * 32 + i * 8;
      gld_lds16(&A [(size_t)(m0 + rb + srow) * Kfull + k0 + lc * 8], &As[rb * 64]);
      gld_lds16(&Bt[(size_t)(n0 + rb + srow) * Kfull + k0 + lc * 8], &Bs[rb * 64]);
    }
    __syncthreads();
#pragma unroll
    for (int kb = 0; kb < 2; kb++) {
      const int pc = ((kb * 4 + quad) ^ (l16 & 7)) * 8;
      bf16x8 a[4], b[4];
#pragma unroll
      for (int f = 0; f < 4; f++) {
        a[f] = *(const bf16x8*)&As[(wm + f * 16 + l16) * 64 + pc];
        b[f] = *(const bf16x8*)&Bs[(wn + f * 16 + l16) * 64 + pc];
      }
#pragma unroll
      for (int fi = 0; fi < 4; fi++)
#pragma unroll
        for (int fj = 0; fj < 4; fj++)
          acc[fi][fj] = __builtin_amdgcn_mfma_f32_16x16x32_bf16(a[fi], b[fj], acc[fi][fj], 0, 0, 0);
    }
    __syncthreads();
  }

  float* Cz = C + (size_t)blockIdx.z * M * N;
#pragma unroll
  for (int fi = 0; fi < 4; fi++) {
    int row0 = m0 + wm + fi * 16 + quad * 4;
#pragma unroll
    for (int fj = 0; fj < 4; fj++) {
      int col = n0 + wn + fj * 16 + l16;
#pragma unroll
      for (int r = 0; r < 4; r++)
        Cz[(size_t)(row0 + r) * N + col] = acc[fi][fj][r];
    }
  }
}

// ---------------------------------------------------------------- split-K reduce: out = a + b
__global__ __launch_bounds__(256) void add2(const float* __restrict__ a,
                                            const float* __restrict__ b,
                                            float* __restrict__ c, int n4) {
  int i = blockIdx.x * 256 + threadIdx.x;
  if (i >= n4) return;
  f32x4 va = ((const f32x4*)a)[i], vb = ((const f32x4*)b)[i];
  ((f32x4*)c)[i] = va + vb;
}

// ---------------------------------------------------------------- RMSNorm + RoPE; q -> Qb bf16 (pre-scaled), k -> Kb bf16
__global__ __launch_bounds__(64) void rmsnorm_rope_qk(const float* __restrict__ qkv,
                                                      const float* __restrict__ cosT,
                                                      const float* __restrict__ sinT,
                                                      const float* __restrict__ qw,
                                                      const float* __restrict__ kw,
                                                      short* __restrict__ Qb,
                                                      short* __restrict__ Kb) {
  int t    = blockIdx.x;
  int hd   = blockIdx.y;        // 0..35: 0..31 q-heads, 32..35 k-heads
  int b    = t >> 10;
  int s    = t & (S_ - 1);
  int lane = threadIdx.x;
  const float QSC = 0.08838834764831845f * 1.4426950408889634f;  // SCALE*log2(e)
  const float* base;
  const float* w;
  short* dst;
  float osc;
  if (hd < H_) {
    base = qkv + (size_t)t * NQKV + hd * D_;
    w = qw; osc = QSC;
    dst = Qb + (((size_t)b * H_ + hd) * S_ + s) * D_;
  } else {
    base = qkv + (size_t)t * NQKV + H_ * D_ + (hd - H_) * D_;
    w = kw; osc = 1.0f;
    dst = Kb + (((size_t)b * HK_ + (hd - H_)) * S_ + s) * D_;
  }
  float x1 = base[lane], x2 = base[lane + 64];
  float ss = x1 * x1 + x2 * x2;
#pragma unroll
  for (int off = 32; off > 0; off >>= 1) ss += __shfl_xor(ss, off, 64);
  float rn = rsqrtf(ss * (1.0f / 128.0f) + 1e-6f);
  float y1 = x1 * rn * w[lane], y2 = x2 * rn * w[lane + 64];
  float c1 = cosT[s * D_ + lane],      s1 = sinT[s * D_ + lane];
  float c2 = cosT[s * D_ + lane + 64], s2 = sinT[s * D_ + lane + 64];
  dst[lane]      = f2bf((y1 * c1 - y2 * s1) * osc);
  dst[lane + 64] = f2bf((y2 * c2 + y1 * s2) * osc);
}

// ---------------------------------------------------------------- V: fp32 qkv slice -> bf16 transposed [b][kh][D][S]
__global__ __launch_bounds__(256) void v_pack(const float* __restrict__ qkv,
                                              short* __restrict__ Vt) {
  int bk = blockIdx.x;            // 0..7 = b*HK+kh
  int s0 = blockIdx.y * 64;
  int d  = threadIdx.x & 127;
  int sg = threadIdx.x >> 7;
  int b = bk >> 2, kh = bk & 3;
  short buf[32];
  const float* src = qkv + ((size_t)(b * S_ + s0 + sg * 32)) * NQKV + (H_ + HK_) * D_ + kh * D_ + d;
#pragma unroll
  for (int sj = 0; sj < 32; sj++)
    buf[sj] = f2bf(src[(size_t)sj * NQKV]);
  short* dst = Vt + ((size_t)bk * D_ + d) * S_ + s0 + sg * 32;
#pragma unroll
  for (int i = 0; i < 4; i++) ((i32x4*)dst)[i] = ((const i32x4*)buf)[i];
}

// ---------------------------------------------------------------- MFMA flash attention v3
// Q-tile 128/block (wave owns 32 rows via fi=0,1). K/V staged via global_load_lds(16),
// XOR-swizzled [row][64]. K rows = key + 64*dhalf (stride-1 frag reads -> conflict-free).
// B-fragments (bk, bv) shared across both fi halves: 38 ds_read_b128 per wave-ktile vs 72.
// l accumulated via ones-rows in Vs. qt map pairs big+small blocks for CU balance.
__global__ __launch_bounds__(256, 3) void attn_mfma3(const short* __restrict__ Qb,
                                                     const short* __restrict__ Kb,
                                                     const short* __restrict__ Vt,
                                                     short* __restrict__ ctx) {
  const int qmap[8] = {7, 0, 6, 1, 5, 2, 4, 3};   // adjacent pairs sum to 18 ktiles
  const int qt = qmap[blockIdx.x & 7];
  const int h  = blockIdx.y;
  const int b  = blockIdx.z;
  const int kh = h >> 3;          // G = 8
  const int q0 = qt * 128;
  const int tid = threadIdx.x, w = tid >> 6, lane = tid & 63;
  const int quad = lane >> 4, l16 = lane & 15;

  __shared__ short Ks[128 * 64];        // K tile: row = key + 64*dhalf, XOR-swizzled
  __shared__ short Vs[144 * 64];        // V^T tile: row = d (128..143 = ones), XOR-swizzled
  __shared__ short Ps[4][2][16 * 72];   // per-(wave,fi) P [qrow][key]

  // ones rows for the l-column trick
  for (int i = tid; i < 16 * 64; i += 256) Vs[128 * 64 + i] = (short)0x3F80;

  // ---- Q A-frags straight from global: rows fi*64 + w*16 + l16
  const short* Qbase = Qb + (((size_t)b * H_ + h) * S_ + q0) * D_;
  bf16x8 aq[2][4];
#pragma unroll
  for (int fi = 0; fi < 2; fi++)
#pragma unroll
    for (int kb = 0; kb < 4; kb++)
      aq[fi][kb] = *(const bf16x8*)&Qbase[(size_t)(fi * 64 + w * 16 + l16) * D_ + kb * 32 + quad * 8];

  const f32x4 z = {0.f, 0.f, 0.f, 0.f};
  f32x4 O[2][9];                        // nb2=8 is the l column
#pragma unroll
  for (int fi = 0; fi < 2; fi++)
#pragma unroll
    for (int n = 0; n < 9; n++) O[fi][n] = z;
  float m_r[2][4] = {{-1e30f, -1e30f, -1e30f, -1e30f}, {-1e30f, -1e30f, -1e30f, -1e30f}};

  const short* Kbase = Kb + ((size_t)(b * HK_ + kh) * S_) * D_;
  const short* Vbase = Vt + ((size_t)(b * HK_ + kh) * D_) * S_;

  const int srow = lane >> 3;
  const int lc   = (lane & 7) ^ srow;

  const int nkt = 2 * qt + 2;
  for (int kt = 0; kt < nkt; kt++) {
    const int k0 = kt * 64;
    __syncthreads();   // previous iter's readers done (also orders ones-init/Q-loads)
#pragma unroll
    for (int i = 0; i < 4; i++) {
      int rb = w * 32 + i * 8;
      int rr = rb + srow;
      // K row rr: key = rr&63, dhalf = rr>>6
      gld_lds16(&Kbase[(size_t)(k0 + (rr & 63)) * D_ + (rr >> 6) * 64 + lc * 8], &Ks[rb * 64]);
      gld_lds16(&Vbase[(size_t)rr * S_ + k0 + lc * 8], &Vs[rb * 64]);   // V row = d
    }
    __syncthreads();   // drains vmcnt

    const bool do0 = (kt <= 2 * qt);    // fi=0 active; fi=1 active through nkt-1

    // ---- QK^T, both fi share each bk fragment
    f32x4 Sc[2][4];
#pragma unroll
    for (int fi = 0; fi < 2; fi++)
#pragma unroll
      for (int nb = 0; nb < 4; nb++) Sc[fi][nb] = z;
#pragma unroll
    for (int kb = 0; kb < 4; kb++) {
      const int c  = kb * 4 + quad;     // d-chunk 0..15
      const int c7 = c & 7;
      const int rbase = (c >> 3) * 64;  // dhalf row offset
#pragma unroll
      for (int nb = 0; nb < 4; nb++) {
        int rr = rbase + nb * 16 + l16;
        bf16x8 bk = *(const bf16x8*)&Ks[rr * 64 + (c7 ^ (l16 & 7)) * 8];
        Sc[0][nb] = __builtin_amdgcn_mfma_f32_16x16x32_bf16(aq[0][kb], bk, Sc[0][nb], 0, 0, 0);
        Sc[1][nb] = __builtin_amdgcn_mfma_f32_16x16x32_bf16(aq[1][kb], bk, Sc[1][nb], 0, 0, 0);
      }
    }

    // ---- per-fi: mask, online softmax, P write, O rescale
#pragma unroll
    for (int fi = 0; fi < 2; fi++) {
      if (fi == 0 && !do0) continue;
      if (kt == 2 * qt + fi) {   // diagonal tile mask
#pragma unroll
        for (int nb = 0; nb < 4; nb++) {
          int col = k0 + nb * 16 + l16;
#pragma unroll
          for (int r = 0; r < 4; r++) {
            int row = q0 + fi * 64 + w * 16 + quad * 4 + r;
            if (col > row) Sc[fi][nb][r] = -1e30f;
          }
        }
      }
      float alpha[4];
#pragma unroll
      for (int r = 0; r < 4; r++) {
        float mx = fmaxf(fmaxf(Sc[fi][0][r], Sc[fi][1][r]), fmaxf(Sc[fi][2][r], Sc[fi][3][r]));
#pragma unroll
        for (int off = 1; off < 16; off <<= 1) mx = fmaxf(mx, __shfl_xor(mx, off, 64));
        float mn = fmaxf(m_r[fi][r], mx);
        alpha[r] = exp2f(m_r[fi][r] - mn);
        m_r[fi][r] = mn;
#pragma unroll
        for (int nb = 0; nb < 4; nb++) Sc[fi][nb][r] = exp2f(Sc[fi][nb][r] - mn);
      }
#pragma unroll
      for (int nb = 0; nb < 4; nb++)
#pragma unroll
        for (int r = 0; r < 4; r++)
          Ps[w][fi][(quad * 4 + r) * 72 + nb * 16 + l16] = f2bf(Sc[fi][nb][r]);
#pragma unroll
      for (int n = 0; n < 9; n++)
#pragma unroll
        for (int r = 0; r < 4; r++) O[fi][n][r] *= alpha[r];
    }

    // ---- PV: bv shared across fi. A = P [qrow][key], B = V^T rows d; nb2=8 = ones -> l
#pragma unroll
    for (int kb2 = 0; kb2 < 2; kb2++) {
      bf16x8 ap0 = *(const bf16x8*)&Ps[w][0][l16 * 72 + kb2 * 32 + quad * 8];
      bf16x8 ap1 = *(const bf16x8*)&Ps[w][1][l16 * 72 + kb2 * 32 + quad * 8];
      const int c7 = kb2 * 4 + quad;    // key-chunk 0..7
#pragma unroll
      for (int nb2 = 0; nb2 < 9; nb2++) {
        int d = nb2 * 16 + l16;
        bf16x8 bv = *(const bf16x8*)&Vs[d * 64 + (c7 ^ (d & 7)) * 8];
        if (do0) O[0][nb2] = __builtin_amdgcn_mfma_f32_16x16x32_bf16(ap0, bv, O[0][nb2], 0, 0, 0);
        O[1][nb2] = __builtin_amdgcn_mfma_f32_16x16x32_bf16(ap1, bv, O[1][nb2], 0, 0, 0);
      }
    }
  }

  // ---- epilogue: every lane's O[fi][8][r] == l
#pragma unroll
  for (int fi = 0; fi < 2; fi++)
#pragma unroll
    for (int r = 0; r < 4; r++) {
      float inv = 1.0f / O[fi][8][r];
      size_t row = (size_t)(b * S_ + q0 + fi * 64 + w * 16 + quad * 4 + r);
      short* dst = ctx + row * (H_ * D_) + h * D_;
#pragma unroll
      for (int nb2 = 0; nb2 < 8; nb2++)
        dst[nb2 * 16 + l16] = f2bf(O[fi][nb2][r] * inv);
    }
}

// ---------------------------------------------------------------- launch
extern "C" void kernel_launch(void* const* d_in, const int* in_sizes, int n_in,
                              void* d_out, int out_size, void* d_ws, size_t ws_size,
                              hipStream_t stream) {
  (void)in_sizes; (void)n_in; (void)out_size; (void)ws_size;
  const float* hidden = (const float*)d_in[0];
  const float* cosT   = (const float*)d_in[1];
  const float* sinT   = (const float*)d_in[2];
  const float* wqkv   = (const float*)d_in[3];
  const float* qnw    = (const float*)d_in[4];
  const float* knw    = (const float*)d_in[5];
  const float* wo     = (const float*)d_in[6];
  float* out = (float*)d_out;

  char* ws = (char*)d_ws;
  float* qkv = (float*)(ws);                                  // 40 MB (dead after rmsnorm+v_pack)
  short* hb  = (short*)(ws + 41943040);                       // 8 MB: hidden bf16 (dead after gemm1)
  short* wT  = (short*)(ws + 41943040 + 8388608);             // 20 MB: w^T (gemm1), then Qb, then w_o^T
  short* ctx = (short*)(ws + 41943040 + 8388608 + 20971520);  // 16 MB: ctx bf16
  short* Kb  = hb;                                            // 2 MB (after gemm1)
  short* Vt  = hb + 1048576;                                  // 2 MB
  short* Qb  = wT;                                            // 16 MB (after gemm1)
  float* part = (float*)ws;                                   // 32 MB split-K partials (qkv dead by then)

  // 1. hidden -> bf16
  cast_f32_bf16<<<4096, 256, 0, stream>>>(hidden, hb, TOK * HID_ / 4);
  // 2. w_qkv [2048][5120] -> bf16 [5120][2048]
  transpose_cast<<<dim3(NQKV / 32, HID_ / 32), 256, 0, stream>>>(wqkv, wT, HID_, NQKV);
  // 3. qkv = hidden @ w_qkv   (M=2048, N=5120, K=2048)
  gemm_bt128<<<dim3(NQKV / 128, TOK / 128, 1), 256, 0, stream>>>(hb, wT, qkv, TOK, NQKV, HID_, HID_);
  // 4. RMSNorm + RoPE -> Qb (pre-scaled bf16), Kb (bf16)
  rmsnorm_rope_qk<<<dim3(TOK, H_ + HK_), 64, 0, stream>>>(qkv, cosT, sinT, qnw, knw, Qb, Kb);
  // 5. V slice -> bf16 transposed [b][kh][D][S]
  v_pack<<<dim3(B_ * HK_, S_ / 64), 256, 0, stream>>>(qkv, Vt);
  // 6. MFMA causal GQA flash attention -> ctx bf16 [2048][4096]
  attn_mfma3<<<dim3(S_ / 128, H_, B_), 256, 0, stream>>>(Qb, Kb, Vt, ctx);
  // 7. w_o [4096][2048] -> bf16 [2048][4096]   [clobbers Qb — attention done]
  transpose_cast<<<dim3(HID_ / 32, (H_ * D_) / 32), 256, 0, stream>>>(wo, wT, H_ * D_, HID_);
  // 8. out = ctx @ w_o, split-K=2 (512 blocks -> 2/CU co-resident), then reduce
  gemm_bt128<<<dim3(HID_ / 128, TOK / 128, 2), 256, 0, stream>>>(ctx, wT, part, TOK, HID_, H_ * D_, (H_ * D_) / 2);
  add2<<<(TOK * HID_ / 4 + 255) / 256, 256, 0, stream>>>(part, part + (size_t)TOK * HID_, out, TOK * HID_ / 4);
}

// Round 6
// 361.216 us; speedup vs baseline: 1.1397x; 1.1397x over previous
//
#include <hip/hip_runtime.h>

// Problem constants (Qwen3MoE attention prefill)
#define B_   2
#define S_   1024
#define HID_ 2048
#define H_   32
#define HK_  4
#define D_   128
#define NQKV ((H_ + 2 * HK_) * D_)   // 5120
#define TOK  (B_ * S_)               // 2048

typedef short bf16x8  __attribute__((ext_vector_type(8)));  // 8 bf16 (4 VGPRs)
typedef short short4v __attribute__((ext_vector_type(4)));
typedef float f32x4   __attribute__((ext_vector_type(4)));
typedef int   i32x4   __attribute__((ext_vector_type(4)));

__device__ inline short f2bf(float f) {
  unsigned u = __builtin_bit_cast(unsigned, f);
  u += 0x7fffu + ((u >> 16) & 1u);   // round-to-nearest-even
  return (short)(u >> 16);
}

// async global->LDS, 16B per lane; LDS dest is wave-uniform base + lane*16
__device__ __forceinline__ void gld_lds16(const short* g, short* l) {
  __builtin_amdgcn_global_load_lds((__attribute__((address_space(1))) void*)g,
                                   (__attribute__((address_space(3))) void*)l, 16, 0, 0);
}

// ---------------------------------------------------------------- cast fp32 -> bf16
__global__ __launch_bounds__(256) void cast_f32_bf16(const float* __restrict__ in,
                                                     short* __restrict__ out, int n4) {
  int i = blockIdx.x * 256 + threadIdx.x;
  if (i >= n4) return;
  f32x4 v = ((const f32x4*)in)[i];
  short4v o;
  o[0] = f2bf(v[0]); o[1] = f2bf(v[1]); o[2] = f2bf(v[2]); o[3] = f2bf(v[3]);
  ((short4v*)out)[i] = o;
}

// ---------------------------------------------------------------- transpose+cast: [K][N] f32 -> [N][K] bf16
__global__ __launch_bounds__(256) void transpose_cast(const float* __restrict__ in,
                                                      short* __restrict__ out,
                                                      int K, int N) {
  __shared__ float tile[32][33];
  int nb = blockIdx.x * 32, kb = blockIdx.y * 32;
  int c = threadIdx.x & 31, r0 = threadIdx.x >> 5;
#pragma unroll
  for (int i = 0; i < 4; i++) {
    int r = r0 + i * 8;
    tile[r][c] = in[(size_t)(kb + r) * N + nb + c];
  }
  __syncthreads();
#pragma unroll
  for (int i = 0; i < 4; i++) {
    int r = r0 + i * 8;
    out[(size_t)(nb + r) * K + kb + c] = f2bf(tile[c][r]);
  }
}

// ---------------------------------------------------------------- bf16 MFMA GEMM (m97 structure), split-K capable
__global__ __launch_bounds__(256) void gemm_bt128(const short* __restrict__ A,
                                                  const short* __restrict__ Bt,
                                                  float* __restrict__ C,
                                                  int M, int N, int Kfull, int klen) {
  const int tid  = threadIdx.x;
  const int m0   = blockIdx.y * 128;
  const int n0   = blockIdx.x * 128;
  const int kz0  = blockIdx.z * klen;
  const int w    = tid >> 6, lane = tid & 63;
  const int quad = lane >> 4, l16 = lane & 15;
  const int wm   = (w >> 1) * 64, wn = (w & 1) * 64;

  __shared__ short As[128 * 64];   // 16 KB, [row][64], chunks XOR-swizzled
  __shared__ short Bs[128 * 64];

  const f32x4 z = {0.f, 0.f, 0.f, 0.f};
  f32x4 acc[4][4];
#pragma unroll
  for (int i = 0; i < 4; i++)
#pragma unroll
    for (int j = 0; j < 4; j++) acc[i][j] = z;

  const int srow = lane >> 3;           // row within 8-row issue group
  const int lc   = (lane & 7) ^ srow;   // logical chunk this lane fetches

  for (int kk = 0; kk < klen; kk += 64) {
    const int k0 = kz0 + kk;
#pragma unroll
    for (int i = 0; i < 4; i++) {
      int rb = w * 32 + i * 8;
      gld_lds16(&A [(size_t)(m0 + rb + srow) * Kfull + k0 + lc * 8], &As[rb * 64]);
      gld_lds16(&Bt[(size_t)(n0 + rb + srow) * Kfull + k0 + lc * 8], &Bs[rb * 64]);
    }
    __syncthreads();
#pragma unroll
    for (int kb = 0; kb < 2; kb++) {
      const int pc = ((kb * 4 + quad) ^ (l16 & 7)) * 8;
      bf16x8 a[4], b[4];
#pragma unroll
      for (int f = 0; f < 4; f++) {
        a[f] = *(const bf16x8*)&As[(wm + f * 16 + l16) * 64 + pc];
        b[f] = *(const bf16x8*)&Bs[(wn + f * 16 + l16) * 64 + pc];
      }
#pragma unroll
      for (int fi = 0; fi < 4; fi++)
#pragma unroll
        for (int fj = 0; fj < 4; fj++)
          acc[fi][fj] = __builtin_amdgcn_mfma_f32_16x16x32_bf16(a[fi], b[fj], acc[fi][fj], 0, 0, 0);
    }
    __syncthreads();
  }

  float* Cz = C + (size_t)blockIdx.z * M * N;
#pragma unroll
  for (int fi = 0; fi < 4; fi++) {
    int row0 = m0 + wm + fi * 16 + quad * 4;
#pragma unroll
    for (int fj = 0; fj < 4; fj++) {
      int col = n0 + wn + fj * 16 + l16;
#pragma unroll
      for (int r = 0; r < 4; r++)
        Cz[(size_t)(row0 + r) * N + col] = acc[fi][fj][r];
    }
  }
}

// ---------------------------------------------------------------- split-K reduce: out = a + b
__global__ __launch_bounds__(256) void add2(const float* __restrict__ a,
                                            const float* __restrict__ b,
                                            float* __restrict__ c, int n4) {
  int i = blockIdx.x * 256 + threadIdx.x;
  if (i >= n4) return;
  f32x4 va = ((const f32x4*)a)[i], vb = ((const f32x4*)b)[i];
  ((f32x4*)c)[i] = va + vb;
}

// ---------------------------------------------------------------- RMSNorm + RoPE; q -> Qb bf16 (pre-scaled), k -> Kb bf16
__global__ __launch_bounds__(64) void rmsnorm_rope_qk(const float* __restrict__ qkv,
                                                      const float* __restrict__ cosT,
                                                      const float* __restrict__ sinT,
                                                      const float* __restrict__ qw,
                                                      const float* __restrict__ kw,
                                                      short* __restrict__ Qb,
                                                      short* __restrict__ Kb) {
  int t    = blockIdx.x;
  int hd   = blockIdx.y;        // 0..35: 0..31 q-heads, 32..35 k-heads
  int b    = t >> 10;
  int s    = t & (S_ - 1);
  int lane = threadIdx.x;
  const float QSC = 0.08838834764831845f * 1.4426950408889634f;  // SCALE*log2(e)
  const float* base;
  const float* w;
  short* dst;
  float osc;
  if (hd < H_) {
    base = qkv + (size_t)t * NQKV + hd * D_;
    w = qw; osc = QSC;
    dst = Qb + (((size_t)b * H_ + hd) * S_ + s) * D_;
  } else {
    base = qkv + (size_t)t * NQKV + H_ * D_ + (hd - H_) * D_;
    w = kw; osc = 1.0f;
    dst = Kb + (((size_t)b * HK_ + (hd - H_)) * S_ + s) * D_;
  }
  float x1 = base[lane], x2 = base[lane + 64];
  float ss = x1 * x1 + x2 * x2;
#pragma unroll
  for (int off = 32; off > 0; off >>= 1) ss += __shfl_xor(ss, off, 64);
  float rn = rsqrtf(ss * (1.0f / 128.0f) + 1e-6f);
  float y1 = x1 * rn * w[lane], y2 = x2 * rn * w[lane + 64];
  float c1 = cosT[s * D_ + lane],      s1 = sinT[s * D_ + lane];
  float c2 = cosT[s * D_ + lane + 64], s2 = sinT[s * D_ + lane + 64];
  dst[lane]      = f2bf((y1 * c1 - y2 * s1) * osc);
  dst[lane + 64] = f2bf((y2 * c2 + y1 * s2) * osc);
}

// ---------------------------------------------------------------- V: fp32 qkv slice -> bf16 transposed [b][kh][D][S]
__global__ __launch_bounds__(256) void v_pack(const float* __restrict__ qkv,
                                              short* __restrict__ Vt) {
  int bk = blockIdx.x;            // 0..7 = b*HK+kh
  int s0 = blockIdx.y * 64;
  int d  = threadIdx.x & 127;
  int sg = threadIdx.x >> 7;
  int b = bk >> 2, kh = bk & 3;
  short buf[32];
  const float* src = qkv + ((size_t)(b * S_ + s0 + sg * 32)) * NQKV + (H_ + HK_) * D_ + kh * D_ + d;
#pragma unroll
  for (int sj = 0; sj < 32; sj++)
    buf[sj] = f2bf(src[(size_t)sj * NQKV]);
  short* dst = Vt + ((size_t)bk * D_ + d) * S_ + s0 + sg * 32;
#pragma unroll
  for (int i = 0; i < 4; i++) ((i32x4*)dst)[i] = ((const i32x4*)buf)[i];
}

// ---------------------------------------------------------------- MFMA flash attention v4
// = round-4 attn_mfma2 register structure (no spills, VGPR~128) + two verified wins:
//   (a) K rows = key + 64*dhalf -> stride-1 frag rows, full XOR coverage, conflict-free
//   (b) qmap pairs big+small qt so adjacent blocks sum to constant work
// Q-tile 128/block (wave owns 32 rows via fi=0,1), K/V-tile 64, l via ones-rows.
__global__ __launch_bounds__(256) void attn_mfma4(const short* __restrict__ Qb,
                                                  const short* __restrict__ Kb,
                                                  const short* __restrict__ Vt,
                                                  short* __restrict__ ctx) {
  const int qmap[8] = {7, 0, 6, 1, 5, 2, 4, 3};   // adjacent pairs sum to 18 ktiles
  const int qt = qmap[blockIdx.x & 7];
  const int h  = blockIdx.y;
  const int b  = blockIdx.z;
  const int kh = h >> 3;          // G = 8
  const int q0 = qt * 128;
  const int tid = threadIdx.x, w = tid >> 6, lane = tid & 63;
  const int quad = lane >> 4, l16 = lane & 15;

  __shared__ short Ks[128 * 64];        // K tile: row = key + 64*dhalf, XOR-swizzled
  __shared__ short Vs[144 * 64];        // V^T tile: row = d (128..143 = ones), XOR-swizzled
  __shared__ short Ps[4][2][16 * 72];   // per-(wave,fi) P [qrow][key]

  // ones rows for the l-column trick
  for (int i = tid; i < 16 * 64; i += 256) Vs[128 * 64 + i] = (short)0x3F80;

  // ---- Q A-frags straight from global: rows fi*64 + w*16 + l16
  const short* Qbase = Qb + (((size_t)b * H_ + h) * S_ + q0) * D_;
  bf16x8 aq[2][4];
#pragma unroll
  for (int fi = 0; fi < 2; fi++)
#pragma unroll
    for (int kb = 0; kb < 4; kb++)
      aq[fi][kb] = *(const bf16x8*)&Qbase[(size_t)(fi * 64 + w * 16 + l16) * D_ + kb * 32 + quad * 8];

  const f32x4 z = {0.f, 0.f, 0.f, 0.f};
  f32x4 O[2][9];                        // nb2=8 is the l column
#pragma unroll
  for (int fi = 0; fi < 2; fi++)
#pragma unroll
    for (int n = 0; n < 9; n++) O[fi][n] = z;
  float m_r[2][4] = {{-1e30f, -1e30f, -1e30f, -1e30f}, {-1e30f, -1e30f, -1e30f, -1e30f}};

  const short* Kbase = Kb + ((size_t)(b * HK_ + kh) * S_) * D_;
  const short* Vbase = Vt + ((size_t)(b * HK_ + kh) * D_) * S_;

  const int srow = lane >> 3;
  const int lc   = (lane & 7) ^ srow;

  const int nkt = 2 * qt + 2;
  for (int kt = 0; kt < nkt; kt++) {
    const int k0 = kt * 64;
    __syncthreads();   // previous iter's readers done (also orders ones-init/Q-loads)
#pragma unroll
    for (int i = 0; i < 4; i++) {
      int rb = w * 32 + i * 8;
      int rr = rb + srow;
      // K row rr: key = rr&63, dhalf = rr>>6
      gld_lds16(&Kbase[(size_t)(k0 + (rr & 63)) * D_ + (rr >> 6) * 64 + lc * 8], &Ks[rb * 64]);
      gld_lds16(&Vbase[(size_t)rr * S_ + k0 + lc * 8], &Vs[rb * 64]);   // V row = d
    }
    __syncthreads();   // drains vmcnt

#pragma unroll
    for (int fi = 0; fi < 2; fi++) {
      if (kt > 2 * qt + fi) continue;   // fi=0 skipped on the final tile

      // ---- QK^T: B-rows stride-1 (conflict-free with XOR swizzle)
      f32x4 Sc[4] = {z, z, z, z};
#pragma unroll
      for (int kb = 0; kb < 4; kb++) {
        const int c  = kb * 4 + quad;     // d-chunk 0..15
        const int c7 = c & 7;
        const int rbase = (c >> 3) * 64;  // dhalf row offset
#pragma unroll
        for (int nb = 0; nb < 4; nb++) {
          int rr = rbase + nb * 16 + l16;
          bf16x8 bk = *(const bf16x8*)&Ks[rr * 64 + (c7 ^ (l16 & 7)) * 8];
          Sc[nb] = __builtin_amdgcn_mfma_f32_16x16x32_bf16(aq[fi][kb], bk, Sc[nb], 0, 0, 0);
        }
      }
      if (kt == 2 * qt + fi) {   // diagonal tile mask
#pragma unroll
        for (int nb = 0; nb < 4; nb++) {
          int col = k0 + nb * 16 + l16;
#pragma unroll
          for (int r = 0; r < 4; r++) {
            int row = q0 + fi * 64 + w * 16 + quad * 4 + r;
            if (col > row) Sc[nb][r] = -1e30f;
          }
        }
      }

      // ---- online softmax: max-reduce over l16 lanes only (sum via MFMA ones-column)
      float alpha[4];
#pragma unroll
      for (int r = 0; r < 4; r++) {
        float mx = fmaxf(fmaxf(Sc[0][r], Sc[1][r]), fmaxf(Sc[2][r], Sc[3][r]));
#pragma unroll
        for (int off = 1; off < 16; off <<= 1) mx = fmaxf(mx, __shfl_xor(mx, off, 64));
        float mn = fmaxf(m_r[fi][r], mx);
        alpha[r] = exp2f(m_r[fi][r] - mn);
        m_r[fi][r] = mn;
#pragma unroll
        for (int nb = 0; nb < 4; nb++) Sc[nb][r] = exp2f(Sc[nb][r] - mn);
      }

      // ---- P (C-layout) -> per-(wave,fi) LDS region
#pragma unroll
      for (int nb = 0; nb < 4; nb++)
#pragma unroll
        for (int r = 0; r < 4; r++)
          Ps[w][fi][(quad * 4 + r) * 72 + nb * 16 + l16] = f2bf(Sc[nb][r]);

      // ---- rescale O (incl. l column)
#pragma unroll
      for (int n = 0; n < 9; n++)
#pragma unroll
        for (int r = 0; r < 4; r++) O[fi][n][r] *= alpha[r];

      // ---- PV: A = P [qrow][key], B = V^T rows d (swizzled); nb2=8 = ones -> l
#pragma unroll
      for (int kb2 = 0; kb2 < 2; kb2++) {
        bf16x8 ap = *(const bf16x8*)&Ps[w][fi][l16 * 72 + kb2 * 32 + quad * 8];
        const int c7 = kb2 * 4 + quad;    // key-chunk 0..7
#pragma unroll
        for (int nb2 = 0; nb2 < 9; nb2++) {
          int d = nb2 * 16 + l16;
          bf16x8 bv = *(const bf16x8*)&Vs[d * 64 + (c7 ^ (d & 7)) * 8];
          O[fi][nb2] = __builtin_amdgcn_mfma_f32_16x16x32_bf16(ap, bv, O[fi][nb2], 0, 0, 0);
        }
      }
    }
  }

  // ---- epilogue: every lane's O[fi][8][r] == l
#pragma unroll
  for (int fi = 0; fi < 2; fi++)
#pragma unroll
    for (int r = 0; r < 4; r++) {
      float inv = 1.0f / O[fi][8][r];
      size_t row = (size_t)(b * S_ + q0 + fi * 64 + w * 16 + quad * 4 + r);
      short* dst = ctx + row * (H_ * D_) + h * D_;
#pragma unroll
      for (int nb2 = 0; nb2 < 8; nb2++)
        dst[nb2 * 16 + l16] = f2bf(O[fi][nb2][r] * inv);
    }
}

// ---------------------------------------------------------------- launch
extern "C" void kernel_launch(void* const* d_in, const int* in_sizes, int n_in,
                              void* d_out, int out_size, void* d_ws, size_t ws_size,
                              hipStream_t stream) {
  (void)in_sizes; (void)n_in; (void)out_size; (void)ws_size;
  const float* hidden = (const float*)d_in[0];
  const float* cosT   = (const float*)d_in[1];
  const float* sinT   = (const float*)d_in[2];
  const float* wqkv   = (const float*)d_in[3];
  const float* qnw    = (const float*)d_in[4];
  const float* knw    = (const float*)d_in[5];
  const float* wo     = (const float*)d_in[6];
  float* out = (float*)d_out;

  char* ws = (char*)d_ws;
  float* qkv = (float*)(ws);                                  // 40 MB (dead after rmsnorm+v_pack)
  short* hb  = (short*)(ws + 41943040);                       // 8 MB: hidden bf16 (dead after gemm1)
  short* wT  = (short*)(ws + 41943040 + 8388608);             // 20 MB: w^T (gemm1), then Qb, then w_o^T
  short* ctx = (short*)(ws + 41943040 + 8388608 + 20971520);  // 16 MB: ctx bf16
  short* Kb  = hb;                                            // 2 MB (after gemm1)
  short* Vt  = hb + 1048576;                                  // 2 MB
  short* Qb  = wT;                                            // 16 MB (after gemm1)
  float* part = (float*)ws;                                   // 32 MB split-K partials (qkv dead by then)

  // 1. hidden -> bf16
  cast_f32_bf16<<<4096, 256, 0, stream>>>(hidden, hb, TOK * HID_ / 4);
  // 2. w_qkv [2048][5120] -> bf16 [5120][2048]
  transpose_cast<<<dim3(NQKV / 32, HID_ / 32), 256, 0, stream>>>(wqkv, wT, HID_, NQKV);
  // 3. qkv = hidden @ w_qkv   (M=2048, N=5120, K=2048)
  gemm_bt128<<<dim3(NQKV / 128, TOK / 128, 1), 256, 0, stream>>>(hb, wT, qkv, TOK, NQKV, HID_, HID_);
  // 4. RMSNorm + RoPE -> Qb (pre-scaled bf16), Kb (bf16)
  rmsnorm_rope_qk<<<dim3(TOK, H_ + HK_), 64, 0, stream>>>(qkv, cosT, sinT, qnw, knw, Qb, Kb);
  // 5. V slice -> bf16 transposed [b][kh][D][S]
  v_pack<<<dim3(B_ * HK_, S_ / 64), 256, 0, stream>>>(qkv, Vt);
  // 6. MFMA causal GQA flash attention -> ctx bf16 [2048][4096]
  attn_mfma4<<<dim3(S_ / 128, H_, B_), 256, 0, stream>>>(Qb, Kb, Vt, ctx);
  // 7. w_o [4096][2048] -> bf16 [2048][4096]   [clobbers Qb — attention done]
  transpose_cast<<<dim3(HID_ / 32, (H_ * D_) / 32), 256, 0, stream>>>(wo, wT, H_ * D_, HID_);
  // 8. out = ctx @ w_o, split-K=2 (512 blocks -> 2/CU co-resident), then reduce
  gemm_bt128<<<dim3(HID_ / 128, TOK / 128, 2), 256, 0, stream>>>(ctx, wT, part, TOK, HID_, H_ * D_, (H_ * D_) / 2);
  add2<<<(TOK * HID_ / 4 + 255) / 256, 256, 0, stream>>>(part, part + (size_t)TOK * HID_, out, TOK * HID_ / 4);
}

// Round 7
// 348.389 us; speedup vs baseline: 1.1816x; 1.0368x over previous
//
#include <hip/hip_runtime.h>

// Problem constants (Qwen3MoE attention prefill)
#define B_   2
#define S_   1024
#define HID_ 2048
#define H_   32
#define HK_  4
#define D_   128
#define NQKV ((H_ + 2 * HK_) * D_)   // 5120
#define TOK  (B_ * S_)               // 2048

typedef short bf16x8  __attribute__((ext_vector_type(8)));  // 8 bf16 (4 VGPRs)
typedef short short4v __attribute__((ext_vector_type(4)));
typedef float f32x4   __attribute__((ext_vector_type(4)));
typedef int   i32x4   __attribute__((ext_vector_type(4)));

__device__ inline short f2bf(float f) {
  unsigned u = __builtin_bit_cast(unsigned, f);
  u += 0x7fffu + ((u >> 16) & 1u);   // round-to-nearest-even
  return (short)(u >> 16);
}

// async global->LDS, 16B per lane; LDS dest is wave-uniform base + lane*16
__device__ __forceinline__ void gld_lds16(const short* g, short* l) {
  __builtin_amdgcn_global_load_lds((__attribute__((address_space(1))) void*)g,
                                   (__attribute__((address_space(3))) void*)l, 16, 0, 0);
}

// ---------------------------------------------------------------- cast fp32 -> bf16
__global__ __launch_bounds__(256) void cast_f32_bf16(const float* __restrict__ in,
                                                     short* __restrict__ out, int n4) {
  int i = blockIdx.x * 256 + threadIdx.x;
  if (i >= n4) return;
  f32x4 v = ((const f32x4*)in)[i];
  short4v o;
  o[0] = f2bf(v[0]); o[1] = f2bf(v[1]); o[2] = f2bf(v[2]); o[3] = f2bf(v[3]);
  ((short4v*)out)[i] = o;
}

// ---------------------------------------------------------------- transpose+cast: [K][N] f32 -> [N][K] bf16
__global__ __launch_bounds__(256) void transpose_cast(const float* __restrict__ in,
                                                      short* __restrict__ out,
                                                      int K, int N) {
  __shared__ float tile[32][33];
  int nb = blockIdx.x * 32, kb = blockIdx.y * 32;
  int c = threadIdx.x & 31, r0 = threadIdx.x >> 5;
#pragma unroll
  for (int i = 0; i < 4; i++) {
    int r = r0 + i * 8;
    tile[r][c] = in[(size_t)(kb + r) * N + nb + c];
  }
  __syncthreads();
#pragma unroll
  for (int i = 0; i < 4; i++) {
    int r = r0 + i * 8;
    out[(size_t)(nb + r) * K + kb + c] = f2bf(tile[c][r]);
  }
}

// ---------------------------------------------------------------- bf16 MFMA GEMM (m97 structure), split-K capable
__global__ __launch_bounds__(256) void gemm_bt128(const short* __restrict__ A,
                                                  const short* __restrict__ Bt,
                                                  float* __restrict__ C,
                                                  int M, int N, int Kfull, int klen) {
  const int tid  = threadIdx.x;
  const int m0   = blockIdx.y * 128;
  const int n0   = blockIdx.x * 128;
  const int kz0  = blockIdx.z * klen;
  const int w    = tid >> 6, lane = tid & 63;
  const int quad = lane >> 4, l16 = lane & 15;
  const int wm   = (w >> 1) * 64, wn = (w & 1) * 64;

  __shared__ short As[128 * 64];   // 16 KB, [row][64], chunks XOR-swizzled
  __shared__ short Bs[128 * 64];

  const f32x4 z = {0.f, 0.f, 0.f, 0.f};
  f32x4 acc[4][4];
#pragma unroll
  for (int i = 0; i < 4; i++)
#pragma unroll
    for (int j = 0; j < 4; j++) acc[i][j] = z;

  const int srow = lane >> 3;           // row within 8-row issue group
  const int lc   = (lane & 7) ^ srow;   // logical chunk this lane fetches

  for (int kk = 0; kk < klen; kk += 64) {
    const int k0 = kz0 + kk;
#pragma unroll
    for (int i = 0; i < 4; i++) {
      int rb = w * 32 + i * 8;
      gld_lds16(&A [(size_t)(m0 + rb + srow) * Kfull + k0 + lc * 8], &As[rb * 64]);
      gld_lds16(&Bt[(size_t)(n0 + rb + srow) * Kfull + k0 + lc * 8], &Bs[rb * 64]);
    }
    __syncthreads();
#pragma unroll
    for (int kb = 0; kb < 2; kb++) {
      const int pc = ((kb * 4 + quad) ^ (l16 & 7)) * 8;
      bf16x8 a[4], b[4];
#pragma unroll
      for (int f = 0; f < 4; f++) {
        a[f] = *(const bf16x8*)&As[(wm + f * 16 + l16) * 64 + pc];
        b[f] = *(const bf16x8*)&Bs[(wn + f * 16 + l16) * 64 + pc];
      }
#pragma unroll
      for (int fi = 0; fi < 4; fi++)
#pragma unroll
        for (int fj = 0; fj < 4; fj++)
          acc[fi][fj] = __builtin_amdgcn_mfma_f32_16x16x32_bf16(a[fi], b[fj], acc[fi][fj], 0, 0, 0);
    }
    __syncthreads();
  }

  float* Cz = C + (size_t)blockIdx.z * M * N;
#pragma unroll
  for (int fi = 0; fi < 4; fi++) {
    int row0 = m0 + wm + fi * 16 + quad * 4;
#pragma unroll
    for (int fj = 0; fj < 4; fj++) {
      int col = n0 + wn + fj * 16 + l16;
#pragma unroll
      for (int r = 0; r < 4; r++)
        Cz[(size_t)(row0 + r) * N + col] = acc[fi][fj][r];
    }
  }
}

// ---------------------------------------------------------------- split-K reduce: out = a + b
__global__ __launch_bounds__(256) void add2(const float* __restrict__ a,
                                            const float* __restrict__ b,
                                            float* __restrict__ c, int n4) {
  int i = blockIdx.x * 256 + threadIdx.x;
  if (i >= n4) return;
  f32x4 va = ((const f32x4*)a)[i], vb = ((const f32x4*)b)[i];
  ((f32x4*)c)[i] = va + vb;
}

// ---------------------------------------------------------------- RMSNorm + RoPE; q -> Qb bf16 (pre-scaled), k -> Kb bf16
__global__ __launch_bounds__(64) void rmsnorm_rope_qk(const float* __restrict__ qkv,
                                                      const float* __restrict__ cosT,
                                                      const float* __restrict__ sinT,
                                                      const float* __restrict__ qw,
                                                      const float* __restrict__ kw,
                                                      short* __restrict__ Qb,
                                                      short* __restrict__ Kb) {
  int t    = blockIdx.x;
  int hd   = blockIdx.y;        // 0..35: 0..31 q-heads, 32..35 k-heads
  int b    = t >> 10;
  int s    = t & (S_ - 1);
  int lane = threadIdx.x;
  const float QSC = 0.08838834764831845f * 1.4426950408889634f;  // SCALE*log2(e)
  const float* base;
  const float* w;
  short* dst;
  float osc;
  if (hd < H_) {
    base = qkv + (size_t)t * NQKV + hd * D_;
    w = qw; osc = QSC;
    dst = Qb + (((size_t)b * H_ + hd) * S_ + s) * D_;
  } else {
    base = qkv + (size_t)t * NQKV + H_ * D_ + (hd - H_) * D_;
    w = kw; osc = 1.0f;
    dst = Kb + (((size_t)b * HK_ + (hd - H_)) * S_ + s) * D_;
  }
  float x1 = base[lane], x2 = base[lane + 64];
  float ss = x1 * x1 + x2 * x2;
#pragma unroll
  for (int off = 32; off > 0; off >>= 1) ss += __shfl_xor(ss, off, 64);
  float rn = rsqrtf(ss * (1.0f / 128.0f) + 1e-6f);
  float y1 = x1 * rn * w[lane], y2 = x2 * rn * w[lane + 64];
  float c1 = cosT[s * D_ + lane],      s1 = sinT[s * D_ + lane];
  float c2 = cosT[s * D_ + lane + 64], s2 = sinT[s * D_ + lane + 64];
  dst[lane]      = f2bf((y1 * c1 - y2 * s1) * osc);
  dst[lane + 64] = f2bf((y2 * c2 + y1 * s2) * osc);
}

// ---------------------------------------------------------------- V: fp32 qkv slice -> bf16 transposed [b][kh][D][S]
__global__ __launch_bounds__(256) void v_pack(const float* __restrict__ qkv,
                                              short* __restrict__ Vt) {
  int bk = blockIdx.x;            // 0..7 = b*HK+kh
  int s0 = blockIdx.y * 64;
  int d  = threadIdx.x & 127;
  int sg = threadIdx.x >> 7;
  int b = bk >> 2, kh = bk & 3;
  short buf[32];
  const float* src = qkv + ((size_t)(b * S_ + s0 + sg * 32)) * NQKV + (H_ + HK_) * D_ + kh * D_ + d;
#pragma unroll
  for (int sj = 0; sj < 32; sj++)
    buf[sj] = f2bf(src[(size_t)sj * NQKV]);
  short* dst = Vt + ((size_t)bk * D_ + d) * S_ + s0 + sg * 32;
#pragma unroll
  for (int i = 0; i < 4; i++) ((i32x4*)dst)[i] = ((const i32x4*)buf)[i];
}

// ---------------------------------------------------------------- MFMA flash attention v5: static-max softmax
// |q.k*log2e| <= sqrt(D)*log2e = 16.3 (RMSNormed q,k, Cauchy-Schwarz) -> p = exp2(s-18)
// never overflows, p >= 2^-41 >> bf16 underflow; softmax is scale-invariant so O is exact.
// This makes softmax PER-ELEMENT: no running max / alpha / rescale / shuffles, and QK can
// go nb-outer with both fi sharing every bk read (8 transient VGPRs). PV shares bv too.
// LDS reads per wave-ktile: 38 vs 72 (r6); shuffle ops: 0 vs 32.
__global__ __launch_bounds__(256) void attn_mfma5(const short* __restrict__ Qb,
                                                  const short* __restrict__ Kb,
                                                  const short* __restrict__ Vt,
                                                  short* __restrict__ ctx) {
  const int qmap[8] = {7, 0, 6, 1, 5, 2, 4, 3};   // adjacent pairs sum to 18 ktiles
  const int qt = qmap[blockIdx.x & 7];
  const int h  = blockIdx.y;
  const int b  = blockIdx.z;
  const int kh = h >> 3;          // G = 8
  const int q0 = qt * 128;
  const int tid = threadIdx.x, w = tid >> 6, lane = tid & 63;
  const int quad = lane >> 4, l16 = lane & 15;
  const float MBIAS = 18.0f;      // static softmax max (log2 units)

  __shared__ short Ks[128 * 64];        // K tile: row = key + 64*dhalf, XOR-swizzled
  __shared__ short Vs[144 * 64];        // V^T tile: row = d (128..143 = ones), XOR-swizzled
  __shared__ short Ps[4][2][16 * 72];   // per-(wave,fi) P [qrow][key]

  // ones rows for the l-column trick
  for (int i = tid; i < 16 * 64; i += 256) Vs[128 * 64 + i] = (short)0x3F80;

  // ---- Q A-frags straight from global: rows fi*64 + w*16 + l16
  const short* Qbase = Qb + (((size_t)b * H_ + h) * S_ + q0) * D_;
  bf16x8 aq[2][4];
#pragma unroll
  for (int fi = 0; fi < 2; fi++)
#pragma unroll
    for (int kb = 0; kb < 4; kb++)
      aq[fi][kb] = *(const bf16x8*)&Qbase[(size_t)(fi * 64 + w * 16 + l16) * D_ + kb * 32 + quad * 8];

  const f32x4 z = {0.f, 0.f, 0.f, 0.f};
  f32x4 O[2][9];                        // nb2=8 is the l column
#pragma unroll
  for (int fi = 0; fi < 2; fi++)
#pragma unroll
    for (int n = 0; n < 9; n++) O[fi][n] = z;

  const short* Kbase = Kb + ((size_t)(b * HK_ + kh) * S_) * D_;
  const short* Vbase = Vt + ((size_t)(b * HK_ + kh) * D_) * S_;

  const int srow = lane >> 3;
  const int lc   = (lane & 7) ^ srow;

  const int nkt = 2 * qt + 2;
  for (int kt = 0; kt < nkt; kt++) {
    const int k0 = kt * 64;
    __syncthreads();   // previous iter's readers done (also orders ones-init/Q-loads)
#pragma unroll
    for (int i = 0; i < 4; i++) {
      int rb = w * 32 + i * 8;
      int rr = rb + srow;
      // K row rr: key = rr&63, dhalf = rr>>6
      gld_lds16(&Kbase[(size_t)(k0 + (rr & 63)) * D_ + (rr >> 6) * 64 + lc * 8], &Ks[rb * 64]);
      gld_lds16(&Vbase[(size_t)rr * S_ + k0 + lc * 8], &Vs[rb * 64]);   // V row = d
    }
    __syncthreads();   // drains vmcnt

    // ---- QK^T + static-max softmax + P write, nb-outer, bk shared across fi
#pragma unroll
    for (int nb = 0; nb < 4; nb++) {
      f32x4 s0 = z, s1 = z;
#pragma unroll
      for (int kb = 0; kb < 4; kb++) {
        const int c  = kb * 4 + quad;     // d-chunk 0..15
        const int c7 = c & 7;
        const int rr = (c >> 3) * 64 + nb * 16 + l16;
        bf16x8 bk = *(const bf16x8*)&Ks[rr * 64 + (c7 ^ (l16 & 7)) * 8];
        s0 = __builtin_amdgcn_mfma_f32_16x16x32_bf16(aq[0][kb], bk, s0, 0, 0, 0);
        s1 = __builtin_amdgcn_mfma_f32_16x16x32_bf16(aq[1][kb], bk, s1, 0, 0, 0);
      }
      const int col = k0 + nb * 16 + l16;
#pragma unroll
      for (int r = 0; r < 4; r++) {
        int row0 = q0 + w * 16 + quad * 4 + r;        // fi=0 row
        float p0 = (col > row0) ? 0.0f : exp2f(s0[r] - MBIAS);
        float p1 = (col > row0 + 64) ? 0.0f : exp2f(s1[r] - MBIAS);
        Ps[w][0][(quad * 4 + r) * 72 + nb * 16 + l16] = f2bf(p0);
        Ps[w][1][(quad * 4 + r) * 72 + nb * 16 + l16] = f2bf(p1);
      }
    }

    // ---- PV: bv shared across fi; nb2=8 = ones -> l (self-normalizing scale 2^-18 cancels)
#pragma unroll
    for (int kb2 = 0; kb2 < 2; kb2++) {
      bf16x8 ap0 = *(const bf16x8*)&Ps[w][0][l16 * 72 + kb2 * 32 + quad * 8];
      bf16x8 ap1 = *(const bf16x8*)&Ps[w][1][l16 * 72 + kb2 * 32 + quad * 8];
      const int c7 = kb2 * 4 + quad;    // key-chunk 0..7
#pragma unroll
      for (int nb2 = 0; nb2 < 9; nb2++) {
        int d = nb2 * 16 + l16;
        bf16x8 bv = *(const bf16x8*)&Vs[d * 64 + (c7 ^ (d & 7)) * 8];
        O[0][nb2] = __builtin_amdgcn_mfma_f32_16x16x32_bf16(ap0, bv, O[0][nb2], 0, 0, 0);
        O[1][nb2] = __builtin_amdgcn_mfma_f32_16x16x32_bf16(ap1, bv, O[1][nb2], 0, 0, 0);
      }
    }
  }

  // ---- epilogue: O / l  (l = ones-column accumulator, same 2^-MBIAS scale)
#pragma unroll
  for (int fi = 0; fi < 2; fi++)
#pragma unroll
    for (int r = 0; r < 4; r++) {
      float inv = 1.0f / O[fi][8][r];
      size_t row = (size_t)(b * S_ + q0 + fi * 64 + w * 16 + quad * 4 + r);
      short* dst = ctx + row * (H_ * D_) + h * D_;
#pragma unroll
      for (int nb2 = 0; nb2 < 8; nb2++)
        dst[nb2 * 16 + l16] = f2bf(O[fi][nb2][r] * inv);
    }
}

// ---------------------------------------------------------------- launch
extern "C" void kernel_launch(void* const* d_in, const int* in_sizes, int n_in,
                              void* d_out, int out_size, void* d_ws, size_t ws_size,
                              hipStream_t stream) {
  (void)in_sizes; (void)n_in; (void)out_size; (void)ws_size;
  const float* hidden = (const float*)d_in[0];
  const float* cosT   = (const float*)d_in[1];
  const float* sinT   = (const float*)d_in[2];
  const float* wqkv   = (const float*)d_in[3];
  const float* qnw    = (const float*)d_in[4];
  const float* knw    = (const float*)d_in[5];
  const float* wo     = (const float*)d_in[6];
  float* out = (float*)d_out;

  char* ws = (char*)d_ws;
  float* qkv = (float*)(ws);                                  // 40 MB (dead after rmsnorm+v_pack)
  short* hb  = (short*)(ws + 41943040);                       // 8 MB: hidden bf16 (dead after gemm1)
  short* wT  = (short*)(ws + 41943040 + 8388608);             // 20 MB: w^T (gemm1), then Qb, then w_o^T
  short* ctx = (short*)(ws + 41943040 + 8388608 + 20971520);  // 16 MB: ctx bf16
  short* Kb  = hb;                                            // 2 MB (after gemm1)
  short* Vt  = hb + 1048576;                                  // 2 MB
  short* Qb  = wT;                                            // 16 MB (after gemm1)
  float* part = (float*)ws;                                   // 32 MB split-K partials (qkv dead by then)

  // 1. hidden -> bf16
  cast_f32_bf16<<<4096, 256, 0, stream>>>(hidden, hb, TOK * HID_ / 4);
  // 2. w_qkv [2048][5120] -> bf16 [5120][2048]
  transpose_cast<<<dim3(NQKV / 32, HID_ / 32), 256, 0, stream>>>(wqkv, wT, HID_, NQKV);
  // 3. qkv = hidden @ w_qkv   (M=2048, N=5120, K=2048)
  gemm_bt128<<<dim3(NQKV / 128, TOK / 128, 1), 256, 0, stream>>>(hb, wT, qkv, TOK, NQKV, HID_, HID_);
  // 4. RMSNorm + RoPE -> Qb (pre-scaled bf16), Kb (bf16)
  rmsnorm_rope_qk<<<dim3(TOK, H_ + HK_), 64, 0, stream>>>(qkv, cosT, sinT, qnw, knw, Qb, Kb);
  // 5. V slice -> bf16 transposed [b][kh][D][S]
  v_pack<<<dim3(B_ * HK_, S_ / 64), 256, 0, stream>>>(qkv, Vt);
  // 6. MFMA causal GQA flash attention -> ctx bf16 [2048][4096]
  attn_mfma5<<<dim3(S_ / 128, H_, B_), 256, 0, stream>>>(Qb, Kb, Vt, ctx);
  // 7. w_o [4096][2048] -> bf16 [2048][4096]   [clobbers Qb — attention done]
  transpose_cast<<<dim3(HID_ / 32, (H_ * D_) / 32), 256, 0, stream>>>(wo, wT, H_ * D_, HID_);
  // 8. out = ctx @ w_o, split-K=2 (512 blocks -> 2/CU co-resident), then reduce
  gemm_bt128<<<dim3(HID_ / 128, TOK / 128, 2), 256, 0, stream>>>(ctx, wT, part, TOK, HID_, H_ * D_, (H_ * D_) / 2);
  add2<<<(TOK * HID_ / 4 + 255) / 256, 256, 0, stream>>>(part, part + (size_t)TOK * HID_, out, TOK * HID_ / 4);
}

// Round 8
// 330.871 us; speedup vs baseline: 1.2442x; 1.0529x over previous
//
#include <hip/hip_runtime.h>

// Problem constants (Qwen3MoE attention prefill)
#define B_   2
#define S_   1024
#define HID_ 2048
#define H_   32
#define HK_  4
#define D_   128
#define NQKV ((H_ + 2 * HK_) * D_)   // 5120
#define TOK  (B_ * S_)               // 2048

typedef short bf16x8  __attribute__((ext_vector_type(8)));  // 8 bf16 (4 VGPRs)
typedef short short4v __attribute__((ext_vector_type(4)));
typedef float f32x4   __attribute__((ext_vector_type(4)));
typedef int   i32x4   __attribute__((ext_vector_type(4)));

__device__ inline short f2bf(float f) {
  unsigned u = __builtin_bit_cast(unsigned, f);
  u += 0x7fffu + ((u >> 16) & 1u);   // round-to-nearest-even
  return (short)(u >> 16);
}
__device__ inline float bf2f(short s) {
  return __builtin_bit_cast(float, ((unsigned)(unsigned short)s) << 16);
}

// async global->LDS, 16B per lane; LDS dest is wave-uniform base + lane*16
__device__ __forceinline__ void gld_lds16(const short* g, short* l) {
  __builtin_amdgcn_global_load_lds((__attribute__((address_space(1))) void*)g,
                                   (__attribute__((address_space(3))) void*)l, 16, 0, 0);
}

// ---------------------------------------------------------------- cast fp32 -> bf16
__global__ __launch_bounds__(256) void cast_f32_bf16(const float* __restrict__ in,
                                                     short* __restrict__ out, int n4) {
  int i = blockIdx.x * 256 + threadIdx.x;
  if (i >= n4) return;
  f32x4 v = ((const f32x4*)in)[i];
  short4v o;
  o[0] = f2bf(v[0]); o[1] = f2bf(v[1]); o[2] = f2bf(v[2]); o[3] = f2bf(v[3]);
  ((short4v*)out)[i] = o;
}

// ---------------------------------------------------------------- transpose+cast: [K][N] f32 -> [N][K] bf16
__global__ __launch_bounds__(256) void transpose_cast(const float* __restrict__ in,
                                                      short* __restrict__ out,
                                                      int K, int N) {
  __shared__ float tile[32][33];
  int nb = blockIdx.x * 32, kb = blockIdx.y * 32;
  int c = threadIdx.x & 31, r0 = threadIdx.x >> 5;
#pragma unroll
  for (int i = 0; i < 4; i++) {
    int r = r0 + i * 8;
    tile[r][c] = in[(size_t)(kb + r) * N + nb + c];
  }
  __syncthreads();
#pragma unroll
  for (int i = 0; i < 4; i++) {
    int r = r0 + i * 8;
    out[(size_t)(nb + r) * K + kb + c] = f2bf(tile[c][r]);
  }
}

// ---------------------------------------------------------------- bf16 MFMA GEMM (m97 structure), split-K capable
__global__ __launch_bounds__(256) void gemm_bt128(const short* __restrict__ A,
                                                  const short* __restrict__ Bt,
                                                  float* __restrict__ C,
                                                  int M, int N, int Kfull, int klen) {
  const int tid  = threadIdx.x;
  const int m0   = blockIdx.y * 128;
  const int n0   = blockIdx.x * 128;
  const int kz0  = blockIdx.z * klen;
  const int w    = tid >> 6, lane = tid & 63;
  const int quad = lane >> 4, l16 = lane & 15;
  const int wm   = (w >> 1) * 64, wn = (w & 1) * 64;

  __shared__ short As[128 * 64];   // 16 KB, [row][64], chunks XOR-swizzled
  __shared__ short Bs[128 * 64];

  const f32x4 z = {0.f, 0.f, 0.f, 0.f};
  f32x4 acc[4][4];
#pragma unroll
  for (int i = 0; i < 4; i++)
#pragma unroll
    for (int j = 0; j < 4; j++) acc[i][j] = z;

  const int srow = lane >> 3;           // row within 8-row issue group
  const int lc   = (lane & 7) ^ srow;   // logical chunk this lane fetches

  for (int kk = 0; kk < klen; kk += 64) {
    const int k0 = kz0 + kk;
#pragma unroll
    for (int i = 0; i < 4; i++) {
      int rb = w * 32 + i * 8;
      gld_lds16(&A [(size_t)(m0 + rb + srow) * Kfull + k0 + lc * 8], &As[rb * 64]);
      gld_lds16(&Bt[(size_t)(n0 + rb + srow) * Kfull + k0 + lc * 8], &Bs[rb * 64]);
    }
    __syncthreads();
#pragma unroll
    for (int kb = 0; kb < 2; kb++) {
      const int pc = ((kb * 4 + quad) ^ (l16 & 7)) * 8;
      bf16x8 a[4], b[4];
#pragma unroll
      for (int f = 0; f < 4; f++) {
        a[f] = *(const bf16x8*)&As[(wm + f * 16 + l16) * 64 + pc];
        b[f] = *(const bf16x8*)&Bs[(wn + f * 16 + l16) * 64 + pc];
      }
#pragma unroll
      for (int fi = 0; fi < 4; fi++)
#pragma unroll
        for (int fj = 0; fj < 4; fj++)
          acc[fi][fj] = __builtin_amdgcn_mfma_f32_16x16x32_bf16(a[fi], b[fj], acc[fi][fj], 0, 0, 0);
    }
    __syncthreads();
  }

  float* Cz = C + (size_t)blockIdx.z * M * N;
#pragma unroll
  for (int fi = 0; fi < 4; fi++) {
    int row0 = m0 + wm + fi * 16 + quad * 4;
#pragma unroll
    for (int fj = 0; fj < 4; fj++) {
      int col = n0 + wn + fj * 16 + l16;
#pragma unroll
      for (int r = 0; r < 4; r++)
        Cz[(size_t)(row0 + r) * N + col] = acc[fi][fj][r];
    }
  }
}

// ---------------------------------------------------------------- split-K reduce: out = a + b
__global__ __launch_bounds__(256) void add2(const float* __restrict__ a,
                                            const float* __restrict__ b,
                                            float* __restrict__ c, int n4) {
  int i = blockIdx.x * 256 + threadIdx.x;
  if (i >= n4) return;
  f32x4 va = ((const f32x4*)a)[i], vb = ((const f32x4*)b)[i];
  ((f32x4*)c)[i] = va + vb;
}

// ---------------------------------------------------------------- fused QKV GEMM:
// C-tile (128 tokens x 1 head) stays in regs; epilogue applies per-head RMSNorm + RoPE
// (q/k heads) or transposed store (v heads), writing bf16 Qb/Kb/Vt directly.
// No fp32 qkv materialization. n-tile 128 == D, so the norm reduction is block-local.
// Waves (w, w^1) hold the same rows and complementary d-halves -> RoPE partner value
// is the same lane-slot in the partner wave; exchanged via the dead As/Bs LDS.
__global__ __launch_bounds__(256) void gemm_qkv(const short* __restrict__ A,
                                                const short* __restrict__ Bt,
                                                const float* __restrict__ cosT,
                                                const float* __restrict__ sinT,
                                                const float* __restrict__ qw,
                                                const float* __restrict__ kw,
                                                short* __restrict__ Qb,
                                                short* __restrict__ Kb,
                                                short* __restrict__ Vt) {
  const int tid  = threadIdx.x;
  const int m0   = blockIdx.y * 128;
  const int n0   = blockIdx.x * 128;
  const int w    = tid >> 6, lane = tid & 63;
  const int quad = lane >> 4, l16 = lane & 15;
  const int wm   = (w >> 1) * 64, wn = (w & 1) * 64;

  __shared__ short As[128 * 64];
  __shared__ short Bs[128 * 64];
  __shared__ float ss_lds[4][64];

  const f32x4 z = {0.f, 0.f, 0.f, 0.f};
  f32x4 acc[4][4];
#pragma unroll
  for (int i = 0; i < 4; i++)
#pragma unroll
    for (int j = 0; j < 4; j++) acc[i][j] = z;

  const int srow = lane >> 3;
  const int lc   = (lane & 7) ^ srow;

  for (int k0 = 0; k0 < HID_; k0 += 64) {
#pragma unroll
    for (int i = 0; i < 4; i++) {
      int rb = w * 32 + i * 8;
      gld_lds16(&A [(size_t)(m0 + rb + srow) * HID_ + k0 + lc * 8], &As[rb * 64]);
      gld_lds16(&Bt[(size_t)(n0 + rb + srow) * HID_ + k0 + lc * 8], &Bs[rb * 64]);
    }
    __syncthreads();
#pragma unroll
    for (int kb = 0; kb < 2; kb++) {
      const int pc = ((kb * 4 + quad) ^ (l16 & 7)) * 8;
      bf16x8 a[4], b[4];
#pragma unroll
      for (int f = 0; f < 4; f++) {
        a[f] = *(const bf16x8*)&As[(wm + f * 16 + l16) * 64 + pc];
        b[f] = *(const bf16x8*)&Bs[(wn + f * 16 + l16) * 64 + pc];
      }
#pragma unroll
      for (int fi = 0; fi < 4; fi++)
#pragma unroll
        for (int fj = 0; fj < 4; fj++)
          acc[fi][fj] = __builtin_amdgcn_mfma_f32_16x16x32_bf16(a[fi], b[fj], acc[fi][fj], 0, 0, 0);
    }
    __syncthreads();
  }

  // ---------------- fused epilogue ----------------
  const int hd = n0 >> 7;                 // head slot 0..39 (n-tile == one head)
  const int bb = m0 >> 10;                // batch (m-tiles never cross batch: 1024%128==0)
  const int sW = (m0 & (S_ - 1)) + wm;    // wave's seq-row base

  if (hd >= H_ + HK_) {                   // ---- V head: bf16 transposed store [d][s]
    const int khv = hd - (H_ + HK_);
    short* dstV = Vt + ((size_t)(bb * HK_ + khv) * D_) * S_;
#pragma unroll
    for (int fi = 0; fi < 4; fi++) {
      int s = sW + fi * 16 + quad * 4;
#pragma unroll
      for (int fj = 0; fj < 4; fj++) {
        int d = wn + fj * 16 + l16;
        short4v o;
#pragma unroll
        for (int r = 0; r < 4; r++) o[r] = f2bf(acc[fi][fj][r]);
        *(short4v*)&dstV[(size_t)d * S_ + s] = o;
      }
    }
    return;
  }

  // ---- Q/K head: RMSNorm (row sum-squares over D=128) ----
  float ssp[4][4];
#pragma unroll
  for (int fi = 0; fi < 4; fi++)
#pragma unroll
    for (int r = 0; r < 4; r++) {
      float t = 0.f;
#pragma unroll
      for (int fj = 0; fj < 4; fj++) t += acc[fi][fj][r] * acc[fi][fj][r];
      ssp[fi][r] = t;
    }
#pragma unroll
  for (int off = 1; off < 16; off <<= 1)
#pragma unroll
    for (int fi = 0; fi < 4; fi++)
#pragma unroll
      for (int r = 0; r < 4; r++) ssp[fi][r] += __shfl_xor(ssp[fi][r], off, 64);
  if (l16 == 0)
#pragma unroll
    for (int fi = 0; fi < 4; fi++)
#pragma unroll
      for (int r = 0; r < 4; r++) ss_lds[w][fi * 16 + quad * 4 + r] = ssp[fi][r];
  __syncthreads();
  float rn[4][4];
#pragma unroll
  for (int fi = 0; fi < 4; fi++)
#pragma unroll
    for (int r = 0; r < 4; r++) {
      int row = fi * 16 + quad * 4 + r;
      rn[fi][r] = rsqrtf((ss_lds[w][row] + ss_lds[w ^ 1][row]) * (1.0f / 128.0f) + 1e-6f);
    }
  const float* wv = (hd < H_) ? qw : kw;
  float wgt[4];
#pragma unroll
  for (int fj = 0; fj < 4; fj++) wgt[fj] = wv[wn + fj * 16 + l16];

  // ---- exchange normalized y with partner wave (RoPE d<->d^64) via dead As/Bs ----
  short* xown = (w & 1) ? &Bs[(w >> 1) * 4096] : &As[(w >> 1) * 4096];
  short* xpar = (w & 1) ? &As[(w >> 1) * 4096] : &Bs[(w >> 1) * 4096];
#pragma unroll
  for (int fi = 0; fi < 4; fi++)
#pragma unroll
    for (int fj = 0; fj < 4; fj++) {
      short4v y4;
#pragma unroll
      for (int r = 0; r < 4; r++) y4[r] = f2bf(acc[fi][fj][r] * rn[fi][r] * wgt[fj]);
      *(short4v*)&xown[(((fi * 4 + fj) * 4 + quad) * 16 + l16) * 4] = y4;
    }
  __syncthreads();

  // ---- RoPE + store bf16 (q pre-scaled by SCALE*log2e for the attn exp2 path) ----
  const float sign = (wn == 0) ? -1.0f : 1.0f;
  const float osc  = (hd < H_) ? (0.08838834764831845f * 1.4426950408889634f) : 1.0f;
  short* dstQ = (hd < H_) ? (Qb + (((size_t)bb * H_ + hd) * S_) * D_)
                          : (Kb + (((size_t)bb * HK_ + (hd - H_)) * S_) * D_);
#pragma unroll
  for (int fi = 0; fi < 4; fi++)
#pragma unroll
    for (int fj = 0; fj < 4; fj++) {
      short4v yp4 = *(const short4v*)&xpar[(((fi * 4 + fj) * 4 + quad) * 16 + l16) * 4];
      int d = wn + fj * 16 + l16;
#pragma unroll
      for (int r = 0; r < 4; r++) {
        int s = sW + fi * 16 + quad * 4 + r;
        float y  = acc[fi][fj][r] * rn[fi][r] * wgt[fj];
        float yp = bf2f(yp4[r]);
        float c  = cosT[s * D_ + d];
        float sn = sinT[s * D_ + d];
        dstQ[(size_t)s * D_ + d] = f2bf((y * c + sign * yp * sn) * osc);
      }
    }
}

// ---------------------------------------------------------------- MFMA flash attention v5: static-max softmax
// |q.k*log2e| <= sqrt(D)*log2e = 16.3 (RMSNormed q,k) -> p = exp2(s-18): per-element
// softmax, no running max / rescale / shuffles; l via ones-rows in Vs.
__global__ __launch_bounds__(256) void attn_mfma5(const short* __restrict__ Qb,
                                                  const short* __restrict__ Kb,
                                                  const short* __restrict__ Vt,
                                                  short* __restrict__ ctx) {
  const int qmap[8] = {7, 0, 6, 1, 5, 2, 4, 3};   // adjacent pairs sum to 18 ktiles
  const int qt = qmap[blockIdx.x & 7];
  const int h  = blockIdx.y;
  const int b  = blockIdx.z;
  const int kh = h >> 3;          // G = 8
  const int q0 = qt * 128;
  const int tid = threadIdx.x, w = tid >> 6, lane = tid & 63;
  const int quad = lane >> 4, l16 = lane & 15;
  const float MBIAS = 18.0f;      // static softmax max (log2 units)

  __shared__ short Ks[128 * 64];        // K tile: row = key + 64*dhalf, XOR-swizzled
  __shared__ short Vs[144 * 64];        // V^T tile: row = d (128..143 = ones), XOR-swizzled
  __shared__ short Ps[4][2][16 * 72];   // per-(wave,fi) P [qrow][key]

  for (int i = tid; i < 16 * 64; i += 256) Vs[128 * 64 + i] = (short)0x3F80;

  const short* Qbase = Qb + (((size_t)b * H_ + h) * S_ + q0) * D_;
  bf16x8 aq[2][4];
#pragma unroll
  for (int fi = 0; fi < 2; fi++)
#pragma unroll
    for (int kb = 0; kb < 4; kb++)
      aq[fi][kb] = *(const bf16x8*)&Qbase[(size_t)(fi * 64 + w * 16 + l16) * D_ + kb * 32 + quad * 8];

  const f32x4 z = {0.f, 0.f, 0.f, 0.f};
  f32x4 O[2][9];                        // nb2=8 is the l column
#pragma unroll
  for (int fi = 0; fi < 2; fi++)
#pragma unroll
    for (int n = 0; n < 9; n++) O[fi][n] = z;

  const short* Kbase = Kb + ((size_t)(b * HK_ + kh) * S_) * D_;
  const short* Vbase = Vt + ((size_t)(b * HK_ + kh) * D_) * S_;

  const int srow = lane >> 3;
  const int lc   = (lane & 7) ^ srow;

  const int nkt = 2 * qt + 2;
  for (int kt = 0; kt < nkt; kt++) {
    const int k0 = kt * 64;
    __syncthreads();
#pragma unroll
    for (int i = 0; i < 4; i++) {
      int rb = w * 32 + i * 8;
      int rr = rb + srow;
      gld_lds16(&Kbase[(size_t)(k0 + (rr & 63)) * D_ + (rr >> 6) * 64 + lc * 8], &Ks[rb * 64]);
      gld_lds16(&Vbase[(size_t)rr * S_ + k0 + lc * 8], &Vs[rb * 64]);
    }
    __syncthreads();

    // ---- QK^T + static-max softmax + P write, nb-outer, bk shared across fi
#pragma unroll
    for (int nb = 0; nb < 4; nb++) {
      f32x4 s0 = z, s1 = z;
#pragma unroll
      for (int kb = 0; kb < 4; kb++) {
        const int c  = kb * 4 + quad;
        const int c7 = c & 7;
        const int rr = (c >> 3) * 64 + nb * 16 + l16;
        bf16x8 bk = *(const bf16x8*)&Ks[rr * 64 + (c7 ^ (l16 & 7)) * 8];
        s0 = __builtin_amdgcn_mfma_f32_16x16x32_bf16(aq[0][kb], bk, s0, 0, 0, 0);
        s1 = __builtin_amdgcn_mfma_f32_16x16x32_bf16(aq[1][kb], bk, s1, 0, 0, 0);
      }
      const int col = k0 + nb * 16 + l16;
#pragma unroll
      for (int r = 0; r < 4; r++) {
        int row0 = q0 + w * 16 + quad * 4 + r;
        float p0 = (col > row0) ? 0.0f : exp2f(s0[r] - MBIAS);
        float p1 = (col > row0 + 64) ? 0.0f : exp2f(s1[r] - MBIAS);
        Ps[w][0][(quad * 4 + r) * 72 + nb * 16 + l16] = f2bf(p0);
        Ps[w][1][(quad * 4 + r) * 72 + nb * 16 + l16] = f2bf(p1);
      }
    }

    // ---- PV: bv shared across fi; nb2=8 = ones -> l
#pragma unroll
    for (int kb2 = 0; kb2 < 2; kb2++) {
      bf16x8 ap0 = *(const bf16x8*)&Ps[w][0][l16 * 72 + kb2 * 32 + quad * 8];
      bf16x8 ap1 = *(const bf16x8*)&Ps[w][1][l16 * 72 + kb2 * 32 + quad * 8];
      const int c7 = kb2 * 4 + quad;
#pragma unroll
      for (int nb2 = 0; nb2 < 9; nb2++) {
        int d = nb2 * 16 + l16;
        bf16x8 bv = *(const bf16x8*)&Vs[d * 64 + (c7 ^ (d & 7)) * 8];
        O[0][nb2] = __builtin_amdgcn_mfma_f32_16x16x32_bf16(ap0, bv, O[0][nb2], 0, 0, 0);
        O[1][nb2] = __builtin_amdgcn_mfma_f32_16x16x32_bf16(ap1, bv, O[1][nb2], 0, 0, 0);
      }
    }
  }

  // ---- epilogue: O / l
#pragma unroll
  for (int fi = 0; fi < 2; fi++)
#pragma unroll
    for (int r = 0; r < 4; r++) {
      float inv = 1.0f / O[fi][8][r];
      size_t row = (size_t)(b * S_ + q0 + fi * 64 + w * 16 + quad * 4 + r);
      short* dst = ctx + row * (H_ * D_) + h * D_;
#pragma unroll
      for (int nb2 = 0; nb2 < 8; nb2++)
        dst[nb2 * 16 + l16] = f2bf(O[fi][nb2][r] * inv);
    }
}

// ---------------------------------------------------------------- launch
extern "C" void kernel_launch(void* const* d_in, const int* in_sizes, int n_in,
                              void* d_out, int out_size, void* d_ws, size_t ws_size,
                              hipStream_t stream) {
  (void)in_sizes; (void)n_in; (void)out_size; (void)ws_size;
  const float* hidden = (const float*)d_in[0];
  const float* cosT   = (const float*)d_in[1];
  const float* sinT   = (const float*)d_in[2];
  const float* wqkv   = (const float*)d_in[3];
  const float* qnw    = (const float*)d_in[4];
  const float* knw    = (const float*)d_in[5];
  const float* wo     = (const float*)d_in[6];
  float* out = (float*)d_out;

  char* ws = (char*)d_ws;
  short* Qb  = (short*)ws;                                    // 16 MB (dead after attn)
  short* Kb  = (short*)(ws + 16777216);                       //  2 MB
  short* Vt  = (short*)(ws + 16777216 + 2097152);             //  2 MB
  short* hb  = (short*)(ws + 41943040);                       //  8 MB hidden bf16
  short* wT  = (short*)(ws + 41943040 + 8388608);             // 20 MB w^T (qkv), then w_o^T
  short* ctx = (short*)(ws + 41943040 + 8388608 + 20971520);  // 16 MB ctx bf16
  float* part = (float*)ws;                                   // 32 MB split-K partials (over Qb/Kb/Vt, post-attn)

  // 1. hidden -> bf16
  cast_f32_bf16<<<4096, 256, 0, stream>>>(hidden, hb, TOK * HID_ / 4);
  // 2. w_qkv [2048][5120] -> bf16 [5120][2048]
  transpose_cast<<<dim3(NQKV / 32, HID_ / 32), 256, 0, stream>>>(wqkv, wT, HID_, NQKV);
  // 3. fused qkv-GEMM + RMSNorm + RoPE + V-transpose -> Qb/Kb/Vt bf16 (no fp32 qkv)
  gemm_qkv<<<dim3(NQKV / 128, TOK / 128), 256, 0, stream>>>(hb, wT, cosT, sinT, qnw, knw, Qb, Kb, Vt);
  // 4. MFMA causal GQA flash attention -> ctx bf16 [2048][4096]
  attn_mfma5<<<dim3(S_ / 128, H_, B_), 256, 0, stream>>>(Qb, Kb, Vt, ctx);
  // 5. w_o [4096][2048] -> bf16 [2048][4096]
  transpose_cast<<<dim3(HID_ / 32, (H_ * D_) / 32), 256, 0, stream>>>(wo, wT, H_ * D_, HID_);
  // 6. out = ctx @ w_o, split-K=2 (512 blocks -> 2/CU co-resident), then reduce
  gemm_bt128<<<dim3(HID_ / 128, TOK / 128, 2), 256, 0, stream>>>(ctx, wT, part, TOK, HID_, H_ * D_, (H_ * D_) / 2);
  add2<<<(TOK * HID_ / 4 + 255) / 256, 256, 0, stream>>>(part, part + (size_t)TOK * HID_, out, TOK * HID_ / 4);
}